// Round 7
// baseline (49.547 us; speedup 1.0000x reference)
//
#include <hip/hip_runtime.h>

// InitMotionParams: out[p,n,i] = sum_j R(p,n)[i,j]*means[p,j] + T(p,n)[i]
// R = cont_6d_to_rmat(sum_k softmax(coefs)[p,k] * motion_rots[k,ts[n],:])
// T = sum_k softmax(coefs)[p,k] * motion_transls[k,ts[n],:]
//
// Round-7 structure: table repacked SoA-per-slice: tab[n][c][k] (c=0..8,
// k=0..19) -> one timestep slice is 180 CONTIGUOUS dwords, so the unrolled
// uniform s_load stream merges into dwordx16 runs (few lgkmcnt drains vs 40
// strided-row drains in round 6; SMEM returns out-of-order so every use
// forces a full drain -- fewer, bigger batches win).
// GPT=2: each lane owns gaussians p and p+64; one uniform table load feeds
// both FMA sets (duty per drain x2, softmax work halved, s_load total /2).
// Wave-uniform slice id via readfirstlane (round-4 lesson: lane-dependent
// table addressing kills s_load: SGPR 96->32, 3x slower). No forced
// launch_bounds min-waves (round-2 lesson: spill -> 1.4GB scratch traffic).
// Softmax: no max-subtraction (inputs ~N(0,1)); 1/sum folded only into the
// translation (Gram-Schmidt is scale-invariant in the weights).

constexpr int KK    = 20;
constexpr int BB    = 8;
constexpr int BLK   = 256;
constexpr int GPB   = 128;   // gaussians per block (GPT=2 x 64 lanes)
constexpr int SLICE = 9 * KK; // 180 floats per timestep slice, contiguous

typedef __attribute__((ext_vector_type(2))) float f32x2;

__global__ void gather_tab(const float* __restrict__ motion_rots,    // (K,F,6)
                           const float* __restrict__ motion_transls, // (K,F,3)
                           const int*   __restrict__ ts,             // (B)
                           float* __restrict__ tab,                  // ws
                           int F)
{
    const int tid = threadIdx.x;
    if (tid < BB * KK) {
        const int n = tid / KK, k = tid % KK;
        const int t = ts[n];
        const float* rp = motion_rots    + ((size_t)k * F + t) * 6;
        const float* tp = motion_transls + ((size_t)k * F + t) * 3;
        float* base = tab + (size_t)n * SLICE;   // slice n, component-major
        #pragma unroll
        for (int c = 0; c < 6; ++c) base[c * KK + k] = rp[c];
        #pragma unroll
        for (int c = 0; c < 3; ++c) base[(6 + c) * KK + k] = tp[c];
    }
}

__global__ __launch_bounds__(BLK) void motion_fwd(
    const float* __restrict__ motion_coefs, // (G,K)
    const float* __restrict__ means,        // (G,3)
    const float* __restrict__ tab,          // ws: (B, 9, K) slice-contiguous
    float* __restrict__ out,                // (G,B,3)
    int G)
{
    const int tid  = threadIdx.x;
    // wave-uniform slice group, provably uniform for the compiler:
    const int q    = __builtin_amdgcn_readfirstlane(tid >> 6);  // wave 0..3
    const int lane = tid & 63;
    const long long pb = (long long)blockIdx.x * GPB + lane;    // gaussian 0

    // per-lane state for 2 gaussians: softmax pairs (f32x2 over k), 1/sum, mean
    f32x2 w2[2][10];
    float invs[2];
    float mx[2][3];
    long long pg[2];

    #pragma unroll
    for (int g = 0; g < 2; ++g) {
        pg[g] = pb + 64 * g;
        const long long pc = pg[g] < G ? pg[g] : (long long)G - 1;
        const float4* crow = reinterpret_cast<const float4*>(motion_coefs + pc * KK);
        float s = 0.f;
        #pragma unroll
        for (int u = 0; u < 5; ++u) {
            const float4 v = crow[u];
            const float e0 = __expf(v.x), e1 = __expf(v.y);
            const float e2 = __expf(v.z), e3 = __expf(v.w);
            w2[g][2*u+0] = (f32x2){e0, e1};
            w2[g][2*u+1] = (f32x2){e2, e3};
            s += (e0 + e1) + (e2 + e3);
        }
        invs[g] = __builtin_amdgcn_rcpf(s);
        mx[g][0] = means[pc*3+0];
        mx[g][1] = means[pc*3+1];
        mx[g][2] = means[pc*3+2];
    }

    #pragma unroll
    for (int j = 0; j < 2; ++j) {
        const int sl = q + 4 * j;                       // uniform slice id
        const float* tb = tab + (size_t)sl * SLICE;     // uniform address

        // acc[g][c] accumulates k-pairs; shared table load feeds both g
        f32x2 acc[2][9];
        #pragma unroll
        for (int g = 0; g < 2; ++g)
            #pragma unroll
            for (int c = 0; c < 9; ++c) acc[g][c] = (f32x2){0.f, 0.f};

        #pragma unroll
        for (int c = 0; c < 9; ++c) {
            #pragma unroll
            for (int kk = 0; kk < 10; ++kk) {
                // 180 contiguous dwords per slice -> s_load_dwordx16 merging
                const f32x2 t = *reinterpret_cast<const f32x2*>(tb + c * KK + 2 * kk);
                acc[0][c] += w2[0][kk] * t;
                acc[1][c] += w2[1][kk] * t;
            }
        }

        #pragma unroll
        for (int g = 0; g < 2; ++g) {
            float r[9];
            #pragma unroll
            for (int c = 0; c < 9; ++c) r[c] = acc[g][c].x + acc[g][c].y;

            const float n1 = __builtin_amdgcn_sqrtf(fmaf(r[0], r[0], fmaf(r[1], r[1], r[2]*r[2])));
            const float i1 = __builtin_amdgcn_rcpf(fmaxf(n1, 1e-12f));
            const float b10 = r[0]*i1, b11 = r[1]*i1, b12 = r[2]*i1;

            const float d  = fmaf(b10, r[3], fmaf(b11, r[4], b12*r[5]));
            const float q0 = fmaf(-d, b10, r[3]);
            const float q1 = fmaf(-d, b11, r[4]);
            const float q2 = fmaf(-d, b12, r[5]);
            const float n2 = __builtin_amdgcn_sqrtf(fmaf(q0, q0, fmaf(q1, q1, q2*q2)));
            const float i2 = __builtin_amdgcn_rcpf(fmaxf(n2, 1e-12f));
            const float b20 = q0*i2, b21 = q1*i2, b22 = q2*i2;

            const float b30 = fmaf(b11, b22, -(b12*b21));
            const float b31 = fmaf(b12, b20, -(b10*b22));
            const float b32 = fmaf(b10, b21, -(b11*b20));

            const float u0 = r[6] * invs[g];   // transl gets deferred 1/sum
            const float u1 = r[7] * invs[g];
            const float u2 = r[8] * invs[g];

            const float o0 = fmaf(b10, mx[g][0], fmaf(b20, mx[g][1], fmaf(b30, mx[g][2], u0)));
            const float o1 = fmaf(b11, mx[g][0], fmaf(b21, mx[g][1], fmaf(b31, mx[g][2], u1)));
            const float o2 = fmaf(b12, mx[g][0], fmaf(b22, mx[g][1], fmaf(b32, mx[g][2], u2)));

            if (pg[g] < G) {
                float* op = out + (size_t)pg[g] * (BB*3) + (size_t)sl * 3;
                op[0] = o0; op[1] = o1; op[2] = o2;
            }
        }
    }
}

extern "C" void kernel_launch(void* const* d_in, const int* in_sizes, int n_in,
                              void* d_out, int out_size, void* d_ws, size_t ws_size,
                              hipStream_t stream) {
    const float* motion_rots    = (const float*)d_in[0];
    const float* motion_transls = (const float*)d_in[1];
    const float* motion_coefs   = (const float*)d_in[2];
    const float* means          = (const float*)d_in[3];
    const int*   ts             = (const int*)d_in[4];
    float* out = (float*)d_out;
    float* tab = (float*)d_ws;   // needs BB*SLICE*4 = 5760 B

    const int G = in_sizes[3] / 3;            // means is (G,3)
    const int F = in_sizes[0] / (6 * KK);     // motion_rots is (K,F,6)

    gather_tab<<<1, 192, 0, stream>>>(motion_rots, motion_transls, ts, tab, F);

    const int nblk = (G + GPB - 1) / GPB;     // 128 gaussians per block
    motion_fwd<<<nblk, BLK, 0, stream>>>(motion_coefs, means, tab, out, G);
}

// Round 8
// 34.750 us; speedup vs baseline: 1.4258x; 1.4258x over previous
//
#include <hip/hip_runtime.h>

// InitMotionParams: out[p,n,i] = sum_j R(p,n)[i,j]*means[p,j] + T(p,n)[i]
// R = cont_6d_to_rmat(sum_k softmax(coefs)[p,k] * motion_rots[k,ts[n],:])
// T = sum_k softmax(coefs)[p,k] * motion_transls[k,ts[n],:]
//
// Round-8 = round-6 structure + SoA slice table (ISOLATED change; round 7
// bundled SoA with GPT=2 and regressed: VGPR 48 shows the compiler
// rematerialized doubled per-thread state instead of keeping it live,
// inflating VALU ~2x. Lesson: one structural variable per round.)
//  - table tab[n][c][k]: one timestep slice = 180 CONTIGUOUS dwords ->
//    uniform s_load stream merges into dwordx16 runs (~3 drain batches per
//    slice vs ~8 with strided 12-float rows; SMEM is drain-ordered, so
//    fewer/bigger batches = fewer latency bubbles).
//  - 1 gaussian/thread, 4 waves/block; wave q (readfirstlane -> provably
//    uniform, else s_load dies: round-4 SGPR 96->32 3x slowdown) handles
//    slices q and q+4 for the block's 64 gaussians. 6250 blocks = 24.4
//    waves/SIMD supplied.
//  - NO MFMA: Gram-Schmidt amplifies operand error by 1/|a2p|; min|a2p|
//    over 3.2M samples ~4e-4 (validated by f32 absmax 0.0156), so bf16
//    einsum inputs (~2e-3 rounding) would fail by orders of magnitude.
// Softmax: no max-subtraction (inputs ~N(0,1)); 1/sum folded only into the
// translation (Gram-Schmidt is scale-invariant in the weights).

constexpr int KK    = 20;
constexpr int BB    = 8;
constexpr int BLK   = 256;
constexpr int GPB   = 64;     // gaussians per block (1 per lane, 4 waves)
constexpr int SLICE = 9 * KK; // 180 floats per timestep slice, contiguous

typedef __attribute__((ext_vector_type(2))) float f32x2;

__global__ void gather_tab(const float* __restrict__ motion_rots,    // (K,F,6)
                           const float* __restrict__ motion_transls, // (K,F,3)
                           const int*   __restrict__ ts,             // (B)
                           float* __restrict__ tab,                  // ws
                           int F)
{
    const int tid = threadIdx.x;
    if (tid < BB * KK) {
        const int n = tid / KK, k = tid % KK;
        const int t = ts[n];
        const float* rp = motion_rots    + ((size_t)k * F + t) * 6;
        const float* tp = motion_transls + ((size_t)k * F + t) * 3;
        float* base = tab + (size_t)n * SLICE;   // slice n, component-major
        #pragma unroll
        for (int c = 0; c < 6; ++c) base[c * KK + k] = rp[c];
        #pragma unroll
        for (int c = 0; c < 3; ++c) base[(6 + c) * KK + k] = tp[c];
    }
}

__global__ __launch_bounds__(BLK) void motion_fwd(
    const float* __restrict__ motion_coefs, // (G,K)
    const float* __restrict__ means,        // (G,3)
    const float* __restrict__ tab,          // ws: (B, 9, K) slice-contiguous
    float* __restrict__ out,                // (G,B,3)
    int G)
{
    const int tid  = threadIdx.x;
    // wave-uniform slice group, provably uniform for the compiler:
    const int q    = __builtin_amdgcn_readfirstlane(tid >> 6);  // wave 0..3
    const int lane = tid & 63;
    const long long p  = (long long)blockIdx.x * GPB + lane;
    const long long pc = p < G ? p : (long long)G - 1;          // clamp

    // softmax weights as k-pairs (f32x2 -> pk-math), unnormalized e^c;
    // 1/sum deferred to the translation only.
    f32x2 w2[10];
    float invs;
    {
        const float4* crow = reinterpret_cast<const float4*>(motion_coefs + pc * KK);
        float s = 0.f;
        #pragma unroll
        for (int u = 0; u < 5; ++u) {
            const float4 v = crow[u];
            const float e0 = __expf(v.x), e1 = __expf(v.y);
            const float e2 = __expf(v.z), e3 = __expf(v.w);
            w2[2*u+0] = (f32x2){e0, e1};
            w2[2*u+1] = (f32x2){e2, e3};
            s += (e0 + e1) + (e2 + e3);
        }
        invs = __builtin_amdgcn_rcpf(s);
    }
    const float mx0 = means[pc*3+0], mx1 = means[pc*3+1], mx2 = means[pc*3+2];

    // one timestep slice: k-reduction (uniform s_load operands) + Gram-Schmidt
    auto do_slice = [&](int sl) {
        const float* tb = tab + (size_t)sl * SLICE;   // uniform address

        f32x2 acc[9];
        #pragma unroll
        for (int c = 0; c < 9; ++c) acc[c] = (f32x2){0.f, 0.f};

        #pragma unroll
        for (int c = 0; c < 9; ++c) {
            #pragma unroll
            for (int kk = 0; kk < 10; ++kk) {
                // 180 contiguous dwords/slice -> s_load_dwordx16 merging
                const f32x2 t = *reinterpret_cast<const f32x2*>(tb + c * KK + 2 * kk);
                acc[c] += w2[kk] * t;
            }
        }

        float r[9];
        #pragma unroll
        for (int c = 0; c < 9; ++c) r[c] = acc[c].x + acc[c].y;

        const float n1 = __builtin_amdgcn_sqrtf(fmaf(r[0], r[0], fmaf(r[1], r[1], r[2]*r[2])));
        const float i1 = __builtin_amdgcn_rcpf(fmaxf(n1, 1e-12f));
        const float b10 = r[0]*i1, b11 = r[1]*i1, b12 = r[2]*i1;

        const float d  = fmaf(b10, r[3], fmaf(b11, r[4], b12*r[5]));
        const float q0 = fmaf(-d, b10, r[3]);
        const float q1 = fmaf(-d, b11, r[4]);
        const float q2 = fmaf(-d, b12, r[5]);
        const float n2 = __builtin_amdgcn_sqrtf(fmaf(q0, q0, fmaf(q1, q1, q2*q2)));
        const float i2 = __builtin_amdgcn_rcpf(fmaxf(n2, 1e-12f));
        const float b20 = q0*i2, b21 = q1*i2, b22 = q2*i2;

        const float b30 = fmaf(b11, b22, -(b12*b21));
        const float b31 = fmaf(b12, b20, -(b10*b22));
        const float b32 = fmaf(b10, b21, -(b11*b20));

        const float u0 = r[6] * invs;   // transl gets the deferred 1/sum
        const float u1 = r[7] * invs;
        const float u2 = r[8] * invs;

        const float o0 = fmaf(b10, mx0, fmaf(b20, mx1, fmaf(b30, mx2, u0)));
        const float o1 = fmaf(b11, mx0, fmaf(b21, mx1, fmaf(b31, mx2, u1)));
        const float o2 = fmaf(b12, mx0, fmaf(b22, mx1, fmaf(b32, mx2, u2)));

        if (p < G) {
            float* op = out + (size_t)p * (BB*3) + (size_t)sl * 3;
            op[0] = o0; op[1] = o1; op[2] = o2;
        }
    };

    do_slice(q);
    do_slice(q + 4);
}

extern "C" void kernel_launch(void* const* d_in, const int* in_sizes, int n_in,
                              void* d_out, int out_size, void* d_ws, size_t ws_size,
                              hipStream_t stream) {
    const float* motion_rots    = (const float*)d_in[0];
    const float* motion_transls = (const float*)d_in[1];
    const float* motion_coefs   = (const float*)d_in[2];
    const float* means          = (const float*)d_in[3];
    const int*   ts             = (const int*)d_in[4];
    float* out = (float*)d_out;
    float* tab = (float*)d_ws;   // needs BB*SLICE*4 = 5760 B

    const int G = in_sizes[3] / 3;            // means is (G,3)
    const int F = in_sizes[0] / (6 * KK);     // motion_rots is (K,F,6)

    gather_tab<<<1, 192, 0, stream>>>(motion_rots, motion_transls, ts, tab, F);

    const int nblk = (G + GPB - 1) / GPB;     // 64 gaussians per block
    motion_fwd<<<nblk, BLK, 0, stream>>>(motion_coefs, means, tab, out, G);
}